// Round 1
// baseline (3303.551 us; speedup 1.0000x reference)
//
#include <hip/hip_runtime.h>
#include <math.h>

// Problem constants (B, N, D) = (16, 2048, 128)
constexpr int Bc = 16;
constexpr int Nc = 2048;
constexpr int Dc = 128;
constexpr float SCALE_F = 0.08838834764831845f;  // 1/sqrt(128)

// One wave (64 lanes) per query row; 4 waves per block.
// Online-softmax flash-attention in fp32.
//   - lane j of a 64-col chunk computes score for column m0+j
//   - lane i holds output dims {2i, 2i+1} for the PV accumulation
__global__ __launch_bounds__(256) void attn_fwd(
    const float* __restrict__ Q, const float* __restrict__ K, const float* __restrict__ V,
    const float* __restrict__ bias0, const float* __restrict__ bias1,
    const float* __restrict__ bias2, const float* __restrict__ bias3,
    const int* __restrict__ imask, const int* __restrict__ emask,
    float* __restrict__ out)
{
    __shared__ float q_lds[4][Dc];
    const int wave = threadIdx.x >> 6;
    const int lane = threadIdx.x & 63;
    const int b = blockIdx.y;
    const int n = blockIdx.x * 4 + wave;

    // ---- load this wave's query row (zeroed if embeddings_mask is false) ----
    const size_t row_off = ((size_t)b * Nc + n) * (size_t)Dc;
    float2 q2 = ((const float2*)(Q + row_off))[lane];
    const float em = emask[b * Nc + n] ? 1.0f : 0.0f;
    q_lds[wave][2 * lane]     = q2.x * em;
    q_lds[wave][2 * lane + 1] = q2.y * em;
    __syncthreads();  // uniform prologue barrier; q_lds read-only afterwards

    const float4* qv = (const float4*)(&q_lds[wave][0]);
    const float* Kb  = K + (size_t)b * Nc * Dc;
    const float* Vb  = V + (size_t)b * Nc * Dc;
    const int*   imb = imask + b * Nc;
    const float* br0 = bias0 + (size_t)n * Nc;
    const float* br1 = bias1 + (size_t)n * Nc;
    const float* br2 = bias2 + (size_t)n * Nc;
    const float* br3 = bias3 + (size_t)n * Nc;

    float m_run = -INFINITY;
    float l_run = 0.0f;
    float2 acc = make_float2(0.0f, 0.0f);

    for (int m0 = 0; m0 <= n; m0 += 64) {
        const int cols = min(64, n + 1 - m0);

        // ---- scores: lane j -> column m0+j ----
        float score = -INFINITY;   // causal-masked lanes stay -inf -> p = 0
        float pflag = 0.0f;        // input_mask as float: masked K => V contributes 0
        if (lane < cols) {
            const int m = m0 + lane;
            const float4* kr = (const float4*)(Kb + (size_t)m * Dc);
            float s = 0.0f;
            #pragma unroll
            for (int d = 0; d < Dc / 4; ++d) {
                const float4 a = qv[d];      // LDS broadcast (same addr, conflict-free)
                const float4 k4 = kr[d];     // per-lane own K row, L2-resident
                s += a.x * k4.x;
                s += a.y * k4.y;
                s += a.z * k4.z;
                s += a.w * k4.w;
            }
            const int   im   = imb[m];
            const float bsum = br0[m] + br1[m] + br2[m] + br3[m];
            // reference zeroes K where !input_mask => raw score 0, bias still added
            score = (im ? s : 0.0f) * SCALE_F + bsum;
            pflag = im ? 1.0f : 0.0f;
        }

        // ---- online softmax update (wave-wide) ----
        float cmax = score;
        #pragma unroll
        for (int o = 32; o > 0; o >>= 1) cmax = fmaxf(cmax, __shfl_xor(cmax, o, 64));
        const float m_new = fmaxf(m_run, cmax);       // cmax always finite (col m0 valid)
        const float alpha = __expf(m_run - m_new);    // first chunk: exp(-inf) = 0
        const float p     = __expf(score - m_new);    // causal lanes: exp(-inf) = 0
        float psum = p;
        #pragma unroll
        for (int o = 32; o > 0; o >>= 1) psum += __shfl_xor(psum, o, 64);
        l_run = l_run * alpha + psum;
        m_run = m_new;
        acc.x *= alpha;
        acc.y *= alpha;

        // ---- PV accumulate: broadcast p*flag, coalesced float2 V loads ----
        const float pv = p * pflag;
        for (int j = 0; j < cols; ++j) {
            const float pj = __shfl(pv, j, 64);
            const float2 v2 = ((const float2*)(Vb + (size_t)(m0 + j) * Dc))[lane];
            acc.x += pj * v2.x;
            acc.y += pj * v2.y;
        }
    }

    const float inv = 1.0f / l_run;   // l_run > 0 always (col 0 finite score)
    ((float2*)(out + row_off))[lane] = make_float2(acc.x * inv, acc.y * inv);
}

extern "C" void kernel_launch(void* const* d_in, const int* in_sizes, int n_in,
                              void* d_out, int out_size, void* d_ws, size_t ws_size,
                              hipStream_t stream) {
    // inputs: 0:Q 1:K 2:V 3:bias_dis 4:bias_dtw 5:bias_pattern 6:bias_poi
    //         7:input_mask 8:embeddings_mask 9:causal_mask (unused; analytic tril)
    dim3 grid(Nc / 4, Bc);
    attn_fwd<<<grid, dim3(256), 0, stream>>>(
        (const float*)d_in[0], (const float*)d_in[1], (const float*)d_in[2],
        (const float*)d_in[3], (const float*)d_in[4], (const float*)d_in[5],
        (const float*)d_in[6],
        (const int*)d_in[7], (const int*)d_in[8],
        (float*)d_out);
}

// Round 2
// 366.838 us; speedup vs baseline: 9.0055x; 9.0055x over previous
//
#include <hip/hip_runtime.h>
#include <math.h>

// (B, N, D) = (16, 2048, 128)
constexpr int Bc = 16;
constexpr int Nc = 2048;
constexpr int Dc = 128;
constexpr float SCALE_F = 0.08838834764831845f;  // 1/sqrt(128)

typedef __bf16 bf16x8 __attribute__((ext_vector_type(8)));
typedef __bf16 bf16x4 __attribute__((ext_vector_type(4)));
typedef float  f32x4  __attribute__((ext_vector_type(4)));

// ---- prep: bias_sum = b0+b1+b2+b3 (N*N fp32 into ws) ----
__global__ __launch_bounds__(256) void bias_sum_kernel(
    const float* __restrict__ b0, const float* __restrict__ b1,
    const float* __restrict__ b2, const float* __restrict__ b3,
    float* __restrict__ bs)
{
    const int i = blockIdx.x * 256 + threadIdx.x;   // float4 index
    const float4 a = ((const float4*)b0)[i];
    const float4 c = ((const float4*)b1)[i];
    const float4 d = ((const float4*)b2)[i];
    const float4 e = ((const float4*)b3)[i];
    float4 r;
    r.x = a.x + c.x + d.x + e.x;
    r.y = a.y + c.y + d.y + e.y;
    r.z = a.z + c.z + d.z + e.z;
    r.w = a.w + c.w + d.w + e.w;
    ((float4*)bs)[i] = r;
}

// ---- main: MFMA bf16 flash attention ----
// Block = 256 threads = 4 waves. Wave w owns 16 query rows; block owns 64.
// KV processed in 64-key chunks staged to LDS (K row-major bf16, V transposed bf16).
// MFMA 16x16x32 bf16 layouts (HW-verified):
//   A frag: A[m = lane&15][k = (lane>>4)*8 + j], j=0..7
//   B frag: B[k = (lane>>4)*8 + j][n = lane&15]
//   C/D:    D[row = (lane>>4)*4 + reg][col = lane&15]
__global__ __launch_bounds__(256) void attn_mfma(
    const float* __restrict__ Q, const float* __restrict__ K, const float* __restrict__ V,
    const float* __restrict__ p0, const float* __restrict__ p1,
    const float* __restrict__ p2, const float* __restrict__ p3,
    const int* __restrict__ imask, const int* __restrict__ emask,
    float* __restrict__ out, int nbias)
{
    // padded leading dims: 136*2B=272B (17x16) and 72*2B=144B (9x16):
    // rows stay 16B-aligned, row stride maps to 4-bank offset -> 2-way (free).
    __shared__ __align__(16) __bf16 Klds[64][136];
    __shared__ __align__(16) __bf16 Vt[128][72];
    __shared__ __align__(16) __bf16 Plds[4][16][72];

    const int tid  = threadIdx.x;
    const int w    = tid >> 6;
    const int lane = tid & 63;
    const int quad = lane >> 4;
    const int l15  = lane & 15;
    const int b    = blockIdx.y;
    const int ti   = blockIdx.x;
    const int q0   = ti * 64;        // block's first query row
    const int q0w  = q0 + w * 16;    // wave's first query row

    const float* Qb  = Q + (size_t)b * Nc * Dc;
    const float* Kb  = K + (size_t)b * Nc * Dc;
    const float* Vb  = V + (size_t)b * Nc * Dc;
    const int*   imb = imask + b * Nc;

    // ---- Q fragments in registers (emask + SCALE folded in) ----
    bf16x8 qfrag[4];
    {
        const int row = q0w + l15;
        const float qs = emask[b * Nc + row] ? SCALE_F : 0.0f;
        const float4* qr = (const float4*)(Qb + (size_t)row * Dc);
        #pragma unroll
        for (int kd = 0; kd < 4; ++kd) {
            const float4 x = qr[kd * 8 + quad * 2];
            const float4 y = qr[kd * 8 + quad * 2 + 1];
            qfrag[kd][0] = (__bf16)(x.x * qs);
            qfrag[kd][1] = (__bf16)(x.y * qs);
            qfrag[kd][2] = (__bf16)(x.z * qs);
            qfrag[kd][3] = (__bf16)(x.w * qs);
            qfrag[kd][4] = (__bf16)(y.x * qs);
            qfrag[kd][5] = (__bf16)(y.y * qs);
            qfrag[kd][6] = (__bf16)(y.z * qs);
            qfrag[kd][7] = (__bf16)(y.w * qs);
        }
    }

    f32x4 oacc[8];
    #pragma unroll
    for (int dt = 0; dt < 8; ++dt) { oacc[dt][0] = 0.f; oacc[dt][1] = 0.f; oacc[dt][2] = 0.f; oacc[dt][3] = 0.f; }
    float mrun[4] = {-INFINITY, -INFINITY, -INFINITY, -INFINITY};
    float lrun[4] = {0.f, 0.f, 0.f, 0.f};

    for (int m0 = 0; m0 <= q0; m0 += 64) {
        __syncthreads();  // protect LDS reuse from previous chunk's readers

        // ---- stage K (row-major) and V (transposed), fp32 -> bf16, imask applied ----
        #pragma unroll
        for (int it = 0; it < 8; ++it) {
            const int idx = it * 256 + tid;        // float4 index within 64x128 tile
            const int row = idx >> 5;
            const int c4  = idx & 31;
            const int gm  = m0 + row;
            const float msk = imb[gm] ? 1.0f : 0.0f;
            const float4 kf = ((const float4*)(Kb + (size_t)gm * Dc))[c4];
            const float4 vf = ((const float4*)(Vb + (size_t)gm * Dc))[c4];
            bf16x4 kb;
            kb[0] = (__bf16)(kf.x * msk);
            kb[1] = (__bf16)(kf.y * msk);
            kb[2] = (__bf16)(kf.z * msk);
            kb[3] = (__bf16)(kf.w * msk);
            *(bf16x4*)&Klds[row][c4 * 4] = kb;
            Vt[c4 * 4 + 0][row] = (__bf16)(vf.x * msk);
            Vt[c4 * 4 + 1][row] = (__bf16)(vf.y * msk);
            Vt[c4 * 4 + 2][row] = (__bf16)(vf.z * msk);
            Vt[c4 * 4 + 3][row] = (__bf16)(vf.w * msk);
        }
        __syncthreads();

        // ---- S = (Q*SCALE) K^T : 4 col-tiles x 4 d-chunks ----
        f32x4 sc[4];
        #pragma unroll
        for (int jt = 0; jt < 4; ++jt) { sc[jt][0] = 0.f; sc[jt][1] = 0.f; sc[jt][2] = 0.f; sc[jt][3] = 0.f; }
        #pragma unroll
        for (int jt = 0; jt < 4; ++jt) {
            #pragma unroll
            for (int kd = 0; kd < 4; ++kd) {
                const bf16x8 bfr = *(const bf16x8*)&Klds[jt * 16 + l15][kd * 32 + quad * 8];
                sc[jt] = __builtin_amdgcn_mfma_f32_16x16x32_bf16(qfrag[kd], bfr, sc[jt], 0, 0, 0);
            }
        }

        // ---- bias add + causal mask (C layout: row=quad*4+reg, col=l15) ----
        #pragma unroll
        for (int jt = 0; jt < 4; ++jt) {
            #pragma unroll
            for (int reg = 0; reg < 4; ++reg) {
                const int gr = q0w + quad * 4 + reg;
                const int gc = m0 + jt * 16 + l15;
                const size_t boff = (size_t)gr * Nc + gc;
                float bs = p0[boff];
                if (nbias == 4) bs += p1[boff] + p2[boff] + p3[boff];
                const float s = sc[jt][reg] + bs;
                sc[jt][reg] = (gc > gr) ? -INFINITY : s;
            }
        }

        // ---- online softmax (per reg = per query row) ----
        float mloc[4];
        #pragma unroll
        for (int reg = 0; reg < 4; ++reg)
            mloc[reg] = fmaxf(fmaxf(sc[0][reg], sc[1][reg]), fmaxf(sc[2][reg], sc[3][reg]));
        #pragma unroll
        for (int off = 1; off <= 8; off <<= 1) {
            #pragma unroll
            for (int reg = 0; reg < 4; ++reg)
                mloc[reg] = fmaxf(mloc[reg], __shfl_xor(mloc[reg], off, 64));
        }
        float lloc[4];
        #pragma unroll
        for (int reg = 0; reg < 4; ++reg) {
            const float mn = fmaxf(mrun[reg], mloc[reg]);      // finite: diag col always active
            const float alpha = __expf(mrun[reg] - mn);        // first chunk: exp(-inf)=0
            mrun[reg] = mn;
            lrun[reg] *= alpha;
            #pragma unroll
            for (int dt = 0; dt < 8; ++dt) oacc[dt][reg] *= alpha;
            float ls = 0.f;
            #pragma unroll
            for (int jt = 0; jt < 4; ++jt) {
                const float pv = __expf(sc[jt][reg] - mn);     // masked: exp(-inf)=0
                sc[jt][reg] = pv;
                ls += pv;
            }
            lloc[reg] = ls;
        }
        #pragma unroll
        for (int off = 1; off <= 8; off <<= 1) {
            #pragma unroll
            for (int reg = 0; reg < 4; ++reg)
                lloc[reg] += __shfl_xor(lloc[reg], off, 64);
        }
        #pragma unroll
        for (int reg = 0; reg < 4; ++reg) lrun[reg] += lloc[reg];

        // ---- P: C layout -> LDS -> A layout (bf16) ----
        #pragma unroll
        for (int jt = 0; jt < 4; ++jt)
            #pragma unroll
            for (int reg = 0; reg < 4; ++reg)
                Plds[w][quad * 4 + reg][jt * 16 + l15] = (__bf16)sc[jt][reg];
        // same-wave write->read: compiler inserts lgkmcnt wait; no barrier needed

        // ---- O += P V : 2 k-chunks x 8 d-tiles ----
        #pragma unroll
        for (int kj = 0; kj < 2; ++kj) {
            const bf16x8 pa = *(const bf16x8*)&Plds[w][l15][kj * 32 + quad * 8];
            #pragma unroll
            for (int dt = 0; dt < 8; ++dt) {
                const bf16x8 vb = *(const bf16x8*)&Vt[dt * 16 + l15][kj * 32 + quad * 8];
                oacc[dt] = __builtin_amdgcn_mfma_f32_16x16x32_bf16(pa, vb, oacc[dt], 0, 0, 0);
            }
        }
    }

    // ---- epilogue: O / l ----
    float inv[4];
    #pragma unroll
    for (int reg = 0; reg < 4; ++reg) inv[reg] = 1.0f / lrun[reg];  // lrun > 0 always
    #pragma unroll
    for (int reg = 0; reg < 4; ++reg) {
        const int gr = q0w + quad * 4 + reg;
        float* orow = out + ((size_t)b * Nc + gr) * Dc;
        #pragma unroll
        for (int dt = 0; dt < 8; ++dt)
            orow[dt * 16 + l15] = oacc[dt][reg] * inv[reg];
    }
}

extern "C" void kernel_launch(void* const* d_in, const int* in_sizes, int n_in,
                              void* d_out, int out_size, void* d_ws, size_t ws_size,
                              hipStream_t stream) {
    // inputs: 0:Q 1:K 2:V 3:bias_dis 4:bias_dtw 5:bias_pattern 6:bias_poi
    //         7:input_mask 8:embeddings_mask 9:causal_mask (unused; analytic tril)
    const float* Q  = (const float*)d_in[0];
    const float* K  = (const float*)d_in[1];
    const float* V  = (const float*)d_in[2];
    const float* b0 = (const float*)d_in[3];
    const float* b1 = (const float*)d_in[4];
    const float* b2 = (const float*)d_in[5];
    const float* b3 = (const float*)d_in[6];
    const int* im   = (const int*)d_in[7];
    const int* em   = (const int*)d_in[8];
    float* out      = (float*)d_out;

    const dim3 grid(Nc / 64, Bc);
    const bool use_ws = ws_size >= (size_t)Nc * Nc * sizeof(float);
    if (use_ws) {
        float* bs = (float*)d_ws;
        bias_sum_kernel<<<(Nc * Nc / 4) / 256, 256, 0, stream>>>(b0, b1, b2, b3, bs);
        attn_mfma<<<grid, 256, 0, stream>>>(Q, K, V, bs, bs, bs, bs, im, em, out, 1);
    } else {
        attn_mfma<<<grid, 256, 0, stream>>>(Q, K, V, b0, b1, b2, b3, im, em, out, 4);
    }
}

// Round 3
// 237.074 us; speedup vs baseline: 13.9347x; 1.5474x over previous
//
#include <hip/hip_runtime.h>
#include <math.h>

// (B, N, D) = (16, 2048, 128)
constexpr int Bc = 16;
constexpr int Nc = 2048;
constexpr int Dc = 128;
constexpr int NCHUNK = Nc / 64;          // 32 key-chunks of 64
constexpr float SCALE_F = 0.08838834764831845f;  // 1/sqrt(128)

typedef __bf16 bf16x8 __attribute__((ext_vector_type(8)));
typedef __bf16 bf16x4 __attribute__((ext_vector_type(4)));
typedef float  f32x4  __attribute__((ext_vector_type(4)));

// ws layout (bytes):
//   Kpack: B * 32chunks * 16frags * 64lanes * 16B = 8,388,608
//   Vpack: same                                    = 8,388,608
//   bias_sum: N*N*4                                = 16,777,216
constexpr size_t KPACK_BYTES = (size_t)Bc * NCHUNK * 16 * 64 * 16;
constexpr size_t VPACK_BYTES = KPACK_BYTES;
constexpr size_t BIAS_BYTES  = (size_t)Nc * Nc * 4;
constexpr int CHUNK_ELEMS = 16 * 64 * 8;  // 8192 bf16 = 16KB per chunk

__device__ __forceinline__ void gload_lds16(const __bf16* gsrc, __bf16* ldst) {
    // 16B per lane; LDS dest is wave-uniform base + lane*16 (HW rule).
    __builtin_amdgcn_global_load_lds(
        (const __attribute__((address_space(1))) unsigned int*)gsrc,
        (__attribute__((address_space(3))) unsigned int*)ldst, 16, 0, 0);
}

// ---- prep 1: bias_sum = b0+b1+b2+b3 ----
__global__ __launch_bounds__(256) void bias_sum_kernel(
    const float* __restrict__ b0, const float* __restrict__ b1,
    const float* __restrict__ b2, const float* __restrict__ b3,
    float* __restrict__ bs)
{
    const int i = blockIdx.x * 256 + threadIdx.x;
    const float4 a = ((const float4*)b0)[i];
    const float4 c = ((const float4*)b1)[i];
    const float4 d = ((const float4*)b2)[i];
    const float4 e = ((const float4*)b3)[i];
    float4 r;
    r.x = a.x + c.x + d.x + e.x;
    r.y = a.y + c.y + d.y + e.y;
    r.z = a.z + c.z + d.z + e.z;
    r.w = a.w + c.w + d.w + e.w;
    ((float4*)bs)[i] = r;
}

// ---- prep 2: pack K,V (bf16, imask applied) into MFMA B-fragment order ----
// Per (b, chunk c): Kpack frag f=jt*4+kd, lane l=quad*16+l15, j=0..7:
//     K[m0+jt*16+l15][kd*32+quad*8+j]
// Vpack frag f=kj*8+dt: V[m0+kj*32+quad*8+j][dt*16+l15]
__global__ __launch_bounds__(256) void pack_kv(
    const float* __restrict__ K, const float* __restrict__ V,
    const int* __restrict__ imask,
    __bf16* __restrict__ Kp, __bf16* __restrict__ Vp)
{
    __shared__ __align__(16) __bf16 Ks[64][136];   // 272B rows (mult of 16)
    __shared__ __align__(16) __bf16 Vs[64][136];
    const int tid = threadIdx.x;
    const int c = blockIdx.x, b = blockIdx.y;
    const int m0 = c * 64;
    const float* Kb = K + (size_t)b * Nc * Dc;
    const float* Vb = V + (size_t)b * Nc * Dc;
    const int* imb = imask + b * Nc;

    #pragma unroll
    for (int it = 0; it < 8; ++it) {
        const int idx = it * 256 + tid;
        const int row = idx >> 5;
        const int c4  = idx & 31;
        const int gm  = m0 + row;
        const float msk = imb[gm] ? 1.0f : 0.0f;
        const float4 kf = ((const float4*)(Kb + (size_t)gm * Dc))[c4];
        const float4 vf = ((const float4*)(Vb + (size_t)gm * Dc))[c4];
        bf16x4 kb, vb;
        kb[0] = (__bf16)(kf.x * msk); kb[1] = (__bf16)(kf.y * msk);
        kb[2] = (__bf16)(kf.z * msk); kb[3] = (__bf16)(kf.w * msk);
        vb[0] = (__bf16)(vf.x * msk); vb[1] = (__bf16)(vf.y * msk);
        vb[2] = (__bf16)(vf.z * msk); vb[3] = (__bf16)(vf.w * msk);
        *(bf16x4*)&Ks[row][c4 * 4] = kb;
        *(bf16x4*)&Vs[row][c4 * 4] = vb;
    }
    __syncthreads();

    const size_t chunk_base = (size_t)(b * NCHUNK + c) * CHUNK_ELEMS;
    #pragma unroll
    for (int i = 0; i < 4; ++i) {
        const int s = i * 256 + tid;     // slice id: 16 frags x 64 lanes
        const int f = s >> 6;
        const int l = s & 63;
        const int quad = (l >> 4) & 3;
        const int l15  = l & 15;
        // K slice: contiguous 8 d at row jt*16+l15
        {
            const int jt = f >> 2, kd = f & 3;
            const bf16x8 kv = *(const bf16x8*)&Ks[jt * 16 + l15][kd * 32 + quad * 8];
            *(bf16x8*)&Kp[chunk_base + (size_t)f * 512 + l * 8] = kv;
        }
        // V slice: gather 8 keys at column dt*16+l15
        {
            const int kj = f >> 3, dt = f & 7;
            bf16x8 vv;
            #pragma unroll
            for (int j = 0; j < 8; ++j)
                vv[j] = Vs[kj * 32 + quad * 8 + j][dt * 16 + l15];
            *(bf16x8*)&Vp[chunk_base + (size_t)f * 512 + l * 8] = vv;
        }
    }
}

// ---- main: MFMA flash attention, packed K/V via global_load_lds ----
// Block = 4 waves, 64 q-rows. Work-balance remap: co-resident pair
// (x,y),(x,y+8) gets ti = x and 31-x -> constant 33 chunk-units per CU.
__global__ __launch_bounds__(256) void attn_packed(
    const float* __restrict__ Q,
    const __bf16* __restrict__ Kp, const __bf16* __restrict__ Vp,
    const float* __restrict__ p0, const float* __restrict__ p1,
    const float* __restrict__ p2, const float* __restrict__ p3,
    const int* __restrict__ emask, float* __restrict__ out, int nbias)
{
    __shared__ __align__(16) __bf16 Kl[16 * 512];     // 16KB, fragment order
    __shared__ __align__(16) __bf16 Vl[16 * 512];     // 16KB
    __shared__ __align__(16) __bf16 Pl[4][16][72];    // 144B rows (mult of 16)

    const int tid  = threadIdx.x;
    const int w    = tid >> 6;
    const int lane = tid & 63;
    const int quad = lane >> 4;
    const int l15  = lane & 15;
    const int x = blockIdx.x, y = blockIdx.y;
    const int ti = (y < 8) ? x : (31 - x);            // balance remap
    const int b  = ((y & 7) << 1) | (y >> 3);
    const int q0  = ti * 64;
    const int q0w = q0 + w * 16;

    const float* Qb = Q + (size_t)b * Nc * Dc;

    // ---- Q fragments (emask + SCALE folded) ----
    bf16x8 qfrag[4];
    {
        const int row = q0w + l15;
        const float qs = emask[b * Nc + row] ? SCALE_F : 0.0f;
        const float4* qr = (const float4*)(Qb + (size_t)row * Dc);
        #pragma unroll
        for (int kd = 0; kd < 4; ++kd) {
            const float4 xx = qr[kd * 8 + quad * 2];
            const float4 yy = qr[kd * 8 + quad * 2 + 1];
            qfrag[kd][0] = (__bf16)(xx.x * qs); qfrag[kd][1] = (__bf16)(xx.y * qs);
            qfrag[kd][2] = (__bf16)(xx.z * qs); qfrag[kd][3] = (__bf16)(xx.w * qs);
            qfrag[kd][4] = (__bf16)(yy.x * qs); qfrag[kd][5] = (__bf16)(yy.y * qs);
            qfrag[kd][6] = (__bf16)(yy.z * qs); qfrag[kd][7] = (__bf16)(yy.w * qs);
        }
    }

    f32x4 oacc[8];
    #pragma unroll
    for (int dt = 0; dt < 8; ++dt) { oacc[dt][0]=0.f; oacc[dt][1]=0.f; oacc[dt][2]=0.f; oacc[dt][3]=0.f; }
    float mrun[4] = {-INFINITY, -INFINITY, -INFINITY, -INFINITY};
    float lrun[4] = {0.f, 0.f, 0.f, 0.f};

    for (int c = 0; c <= ti; ++c) {
        const int m0 = c * 64;
        __syncthreads();   // prior chunk's readers done before LDS overwrite

        // ---- stage packed K,V: 16B/lane, lane-contiguous, no VALU ----
        const __bf16* gK = Kp + (size_t)(b * NCHUNK + c) * CHUNK_ELEMS;
        const __bf16* gV = Vp + (size_t)(b * NCHUNK + c) * CHUNK_ELEMS;
        #pragma unroll
        for (int i = 0; i < 4; ++i) {
            const int seg = w * 4 + i;                 // 1KB per wave-issue
            gload_lds16(gK + seg * 512 + lane * 8, Kl + seg * 512);
            gload_lds16(gV + seg * 512 + lane * 8, Vl + seg * 512);
        }

        // ---- bias loads (registers; overlap with LDS DMA) ----
        float bsv[4][4];
        #pragma unroll
        for (int jt = 0; jt < 4; ++jt) {
            #pragma unroll
            for (int reg = 0; reg < 4; ++reg) {
                const int gr = q0w + quad * 4 + reg;
                const size_t boff = (size_t)gr * Nc + m0 + jt * 16 + l15;
                float v = p0[boff];
                if (nbias == 4) v += p1[boff] + p2[boff] + p3[boff];
                bsv[jt][reg] = v;
            }
        }
        __syncthreads();   // drains vmcnt: global_load_lds complete

        // ---- S = (Q*SCALE) K^T ----
        f32x4 sc[4];
        #pragma unroll
        for (int jt = 0; jt < 4; ++jt) { sc[jt][0]=0.f; sc[jt][1]=0.f; sc[jt][2]=0.f; sc[jt][3]=0.f; }
        #pragma unroll
        for (int jt = 0; jt < 4; ++jt) {
            #pragma unroll
            for (int kd = 0; kd < 4; ++kd) {
                const bf16x8 bfr = *(const bf16x8*)&Kl[(jt * 4 + kd) * 512 + lane * 8];
                sc[jt] = __builtin_amdgcn_mfma_f32_16x16x32_bf16(qfrag[kd], bfr, sc[jt], 0, 0, 0);
            }
        }

        // ---- bias add (+ causal only on diagonal chunk) ----
        if (c == ti) {
            #pragma unroll
            for (int jt = 0; jt < 4; ++jt)
                #pragma unroll
                for (int reg = 0; reg < 4; ++reg) {
                    const int gr = q0w + quad * 4 + reg;
                    const int gc = m0 + jt * 16 + l15;
                    const float s = sc[jt][reg] + bsv[jt][reg];
                    sc[jt][reg] = (gc > gr) ? -INFINITY : s;
                }
        } else {
            #pragma unroll
            for (int jt = 0; jt < 4; ++jt)
                #pragma unroll
                for (int reg = 0; reg < 4; ++reg)
                    sc[jt][reg] += bsv[jt][reg];
        }

        // ---- online softmax (row = quad*4+reg, spread over 16 lanes) ----
        float mloc[4];
        #pragma unroll
        for (int reg = 0; reg < 4; ++reg)
            mloc[reg] = fmaxf(fmaxf(sc[0][reg], sc[1][reg]), fmaxf(sc[2][reg], sc[3][reg]));
        #pragma unroll
        for (int off = 1; off <= 8; off <<= 1)
            #pragma unroll
            for (int reg = 0; reg < 4; ++reg)
                mloc[reg] = fmaxf(mloc[reg], __shfl_xor(mloc[reg], off, 64));
        float lloc[4];
        #pragma unroll
        for (int reg = 0; reg < 4; ++reg) {
            const float mn = fmaxf(mrun[reg], mloc[reg]);
            const float alpha = __expf(mrun[reg] - mn);
            mrun[reg] = mn;
            lrun[reg] *= alpha;
            #pragma unroll
            for (int dt = 0; dt < 8; ++dt) oacc[dt][reg] *= alpha;
            float ls = 0.f;
            #pragma unroll
            for (int jt = 0; jt < 4; ++jt) {
                const float pv = __expf(sc[jt][reg] - mn);
                sc[jt][reg] = pv;
                ls += pv;
            }
            lloc[reg] = ls;
        }
        #pragma unroll
        for (int off = 1; off <= 8; off <<= 1)
            #pragma unroll
            for (int reg = 0; reg < 4; ++reg)
                lloc[reg] += __shfl_xor(lloc[reg], off, 64);
        #pragma unroll
        for (int reg = 0; reg < 4; ++reg) lrun[reg] += lloc[reg];

        // ---- P: C-layout -> LDS -> A-layout ----
        #pragma unroll
        for (int jt = 0; jt < 4; ++jt)
            #pragma unroll
            for (int reg = 0; reg < 4; ++reg)
                Pl[w][quad * 4 + reg][jt * 16 + l15] = (__bf16)sc[jt][reg];
        // same-wave write->read; compiler inserts lgkmcnt wait

        // ---- O += P V ----
        #pragma unroll
        for (int kj = 0; kj < 2; ++kj) {
            const bf16x8 pa = *(const bf16x8*)&Pl[w][l15][kj * 32 + quad * 8];
            #pragma unroll
            for (int dt = 0; dt < 8; ++dt) {
                const bf16x8 vb = *(const bf16x8*)&Vl[(kj * 8 + dt) * 512 + lane * 8];
                oacc[dt] = __builtin_amdgcn_mfma_f32_16x16x32_bf16(pa, vb, oacc[dt], 0, 0, 0);
            }
        }
    }

    // ---- epilogue ----
    #pragma unroll
    for (int reg = 0; reg < 4; ++reg) {
        const float inv = 1.0f / lrun[reg];
        const int gr = q0w + quad * 4 + reg;
        float* orow = out + ((size_t)b * Nc + gr) * Dc;
        #pragma unroll
        for (int dt = 0; dt < 8; ++dt)
            orow[dt * 16 + l15] = oacc[dt][reg] * inv;
    }
}

// ---- legacy fallback (in-kernel staging) for tiny ws ----
__global__ __launch_bounds__(256) void attn_mfma_legacy(
    const float* __restrict__ Q, const float* __restrict__ K, const float* __restrict__ V,
    const float* __restrict__ p0, const float* __restrict__ p1,
    const float* __restrict__ p2, const float* __restrict__ p3,
    const int* __restrict__ imask, const int* __restrict__ emask,
    float* __restrict__ out, int nbias)
{
    __shared__ __align__(16) __bf16 Klds[64][136];
    __shared__ __align__(16) __bf16 Vt[128][72];
    __shared__ __align__(16) __bf16 Plds[4][16][72];
    const int tid  = threadIdx.x;
    const int w    = tid >> 6;
    const int lane = tid & 63;
    const int quad = lane >> 6 ? 0 : (lane >> 4);
    const int l15  = lane & 15;
    const int b = blockIdx.y;
    const int x = blockIdx.x, yy = blockIdx.y;
    const int ti = (yy < 8) ? x : (31 - x);
    const int q0 = ti * 64, q0w = q0 + w * 16;
    const float* Qb = Q + (size_t)b * Nc * Dc;
    const float* Kb = K + (size_t)b * Nc * Dc;
    const float* Vb = V + (size_t)b * Nc * Dc;
    const int* imb = imask + b * Nc;

    bf16x8 qfrag[4];
    {
        const int row = q0w + l15;
        const float qs = emask[b * Nc + row] ? SCALE_F : 0.0f;
        const float4* qr = (const float4*)(Qb + (size_t)row * Dc);
        #pragma unroll
        for (int kd = 0; kd < 4; ++kd) {
            const float4 xv = qr[kd * 8 + quad * 2];
            const float4 yv = qr[kd * 8 + quad * 2 + 1];
            qfrag[kd][0]=(__bf16)(xv.x*qs); qfrag[kd][1]=(__bf16)(xv.y*qs);
            qfrag[kd][2]=(__bf16)(xv.z*qs); qfrag[kd][3]=(__bf16)(xv.w*qs);
            qfrag[kd][4]=(__bf16)(yv.x*qs); qfrag[kd][5]=(__bf16)(yv.y*qs);
            qfrag[kd][6]=(__bf16)(yv.z*qs); qfrag[kd][7]=(__bf16)(yv.w*qs);
        }
    }
    f32x4 oacc[8];
    #pragma unroll
    for (int dt = 0; dt < 8; ++dt){oacc[dt][0]=0.f;oacc[dt][1]=0.f;oacc[dt][2]=0.f;oacc[dt][3]=0.f;}
    float mrun[4]={-INFINITY,-INFINITY,-INFINITY,-INFINITY}, lrun[4]={0.f,0.f,0.f,0.f};

    for (int m0 = 0; m0 <= q0; m0 += 64) {
        __syncthreads();
        #pragma unroll
        for (int it = 0; it < 8; ++it) {
            const int idx = it * 256 + tid;
            const int row = idx >> 5, c4 = idx & 31;
            const int gm = m0 + row;
            const float msk = imb[gm] ? 1.0f : 0.0f;
            const float4 kf = ((const float4*)(Kb + (size_t)gm * Dc))[c4];
            const float4 vf = ((const float4*)(Vb + (size_t)gm * Dc))[c4];
            bf16x4 kb;
            kb[0]=(__bf16)(kf.x*msk); kb[1]=(__bf16)(kf.y*msk);
            kb[2]=(__bf16)(kf.z*msk); kb[3]=(__bf16)(kf.w*msk);
            *(bf16x4*)&Klds[row][c4*4] = kb;
            Vt[c4*4+0][row]=(__bf16)(vf.x*msk); Vt[c4*4+1][row]=(__bf16)(vf.y*msk);
            Vt[c4*4+2][row]=(__bf16)(vf.z*msk); Vt[c4*4+3][row]=(__bf16)(vf.w*msk);
        }
        __syncthreads();
        f32x4 sc[4];
        #pragma unroll
        for (int jt = 0; jt < 4; ++jt){sc[jt][0]=0.f;sc[jt][1]=0.f;sc[jt][2]=0.f;sc[jt][3]=0.f;}
        #pragma unroll
        for (int jt = 0; jt < 4; ++jt)
            #pragma unroll
            for (int kd = 0; kd < 4; ++kd) {
                const bf16x8 bfr = *(const bf16x8*)&Klds[jt*16+l15][kd*32+quad*8];
                sc[jt] = __builtin_amdgcn_mfma_f32_16x16x32_bf16(qfrag[kd], bfr, sc[jt], 0, 0, 0);
            }
        #pragma unroll
        for (int jt = 0; jt < 4; ++jt)
            #pragma unroll
            for (int reg = 0; reg < 4; ++reg) {
                const int gr = q0w + quad*4 + reg;
                const int gc = m0 + jt*16 + l15;
                const size_t boff = (size_t)gr * Nc + gc;
                float bsx = p0[boff];
                if (nbias == 4) bsx += p1[boff] + p2[boff] + p3[boff];
                const float s = sc[jt][reg] + bsx;
                sc[jt][reg] = (gc > gr) ? -INFINITY : s;
            }
        float mloc[4];
        #pragma unroll
        for (int reg = 0; reg < 4; ++reg)
            mloc[reg] = fmaxf(fmaxf(sc[0][reg], sc[1][reg]), fmaxf(sc[2][reg], sc[3][reg]));
        #pragma unroll
        for (int off = 1; off <= 8; off <<= 1)
            #pragma unroll
            for (int reg = 0; reg < 4; ++reg)
                mloc[reg] = fmaxf(mloc[reg], __shfl_xor(mloc[reg], off, 64));
        float lloc[4];
        #pragma unroll
        for (int reg = 0; reg < 4; ++reg) {
            const float mn = fmaxf(mrun[reg], mloc[reg]);
            const float alpha = __expf(mrun[reg] - mn);
            mrun[reg] = mn; lrun[reg] *= alpha;
            #pragma unroll
            for (int dt = 0; dt < 8; ++dt) oacc[dt][reg] *= alpha;
            float ls = 0.f;
            #pragma unroll
            for (int jt = 0; jt < 4; ++jt) {
                const float pv = __expf(sc[jt][reg] - mn);
                sc[jt][reg] = pv; ls += pv;
            }
            lloc[reg] = ls;
        }
        #pragma unroll
        for (int off = 1; off <= 8; off <<= 1)
            #pragma unroll
            for (int reg = 0; reg < 4; ++reg)
                lloc[reg] += __shfl_xor(lloc[reg], off, 64);
        #pragma unroll
        for (int reg = 0; reg < 4; ++reg) lrun[reg] += lloc[reg];
        #pragma unroll
        for (int jt = 0; jt < 4; ++jt)
            #pragma unroll
            for (int reg = 0; reg < 4; ++reg)
                Plds[w][quad*4+reg][jt*16+l15] = (__bf16)sc[jt][reg];
        #pragma unroll
        for (int kj = 0; kj < 2; ++kj) {
            const bf16x8 pa = *(const bf16x8*)&Plds[w][l15][kj*32+quad*8];
            #pragma unroll
            for (int dt = 0; dt < 8; ++dt) {
                const bf16x8 vb = *(const bf16x8*)&Vt[dt*16+l15][kj*32+quad*8];
                oacc[dt] = __builtin_amdgcn_mfma_f32_16x16x32_bf16(pa, vb, oacc[dt], 0, 0, 0);
            }
        }
    }
    #pragma unroll
    for (int reg = 0; reg < 4; ++reg) {
        const float inv = 1.0f / lrun[reg];
        const int gr = q0w + quad*4 + reg;
        float* orow = out + ((size_t)b * Nc + gr) * Dc;
        #pragma unroll
        for (int dt = 0; dt < 8; ++dt)
            orow[dt*16+l15] = oacc[dt][reg] * inv;
    }
}

extern "C" void kernel_launch(void* const* d_in, const int* in_sizes, int n_in,
                              void* d_out, int out_size, void* d_ws, size_t ws_size,
                              hipStream_t stream) {
    const float* Q  = (const float*)d_in[0];
    const float* K  = (const float*)d_in[1];
    const float* V  = (const float*)d_in[2];
    const float* b0 = (const float*)d_in[3];
    const float* b1 = (const float*)d_in[4];
    const float* b2 = (const float*)d_in[5];
    const float* b3 = (const float*)d_in[6];
    const int* im   = (const int*)d_in[7];
    const int* em   = (const int*)d_in[8];
    float* out      = (float*)d_out;

    const dim3 grid(NCHUNK, Bc);
    const bool havePacks = ws_size >= KPACK_BYTES + VPACK_BYTES;
    const bool haveBias  = ws_size >= KPACK_BYTES + VPACK_BYTES + BIAS_BYTES;

    if (havePacks) {
        __bf16* Kp = (__bf16*)d_ws;
        __bf16* Vp = (__bf16*)((char*)d_ws + KPACK_BYTES);
        pack_kv<<<grid, 256, 0, stream>>>(K, V, im, Kp, Vp);
        if (haveBias) {
            float* bs = (float*)((char*)d_ws + KPACK_BYTES + VPACK_BYTES);
            bias_sum_kernel<<<(Nc * Nc / 4) / 256, 256, 0, stream>>>(b0, b1, b2, b3, bs);
            attn_packed<<<grid, 256, 0, stream>>>(Q, Kp, Vp, bs, bs, bs, bs, em, out, 1);
        } else {
            attn_packed<<<grid, 256, 0, stream>>>(Q, Kp, Vp, b0, b1, b2, b3, em, out, 4);
        }
    } else if (ws_size >= BIAS_BYTES) {
        float* bs = (float*)d_ws;
        bias_sum_kernel<<<(Nc * Nc / 4) / 256, 256, 0, stream>>>(b0, b1, b2, b3, bs);
        attn_mfma_legacy<<<grid, 256, 0, stream>>>(Q, K, V, bs, bs, bs, bs, im, em, out, 1);
    } else {
        attn_mfma_legacy<<<grid, 256, 0, stream>>>(Q, K, V, b0, b1, b2, b3, im, em, out, 4);
    }
}

// Round 4
// 237.058 us; speedup vs baseline: 13.9356x; 1.0001x over previous
//
#include <hip/hip_runtime.h>
#include <math.h>

// (B, N, D) = (16, 2048, 128)
constexpr int Bc = 16;
constexpr int Nc = 2048;
constexpr int Dc = 128;
constexpr int NCHUNK = Nc / 64;          // 32 key-chunks of 64
constexpr float SCALE_F = 0.08838834764831845f;  // 1/sqrt(128)

typedef __bf16 bf16x8 __attribute__((ext_vector_type(8)));
typedef __bf16 bf16x4 __attribute__((ext_vector_type(4)));
typedef float  f32x4  __attribute__((ext_vector_type(4)));

// ws layout: Kpack 8MB | Vpack 8MB | bias_sum 16MB
constexpr size_t KPACK_BYTES = (size_t)Bc * NCHUNK * 16 * 64 * 16;
constexpr size_t VPACK_BYTES = KPACK_BYTES;
constexpr size_t BIAS_BYTES  = (size_t)Nc * Nc * 4;
constexpr int CHUNK_ELEMS = 16 * 64 * 8;  // 8192 bf16 = 16KB per chunk

__device__ __forceinline__ void gload_lds16(const __bf16* gsrc, __bf16* ldst) {
    // 16B per lane; LDS dest is wave-uniform base + lane*16 (HW rule).
    __builtin_amdgcn_global_load_lds(
        (const __attribute__((address_space(1))) unsigned int*)gsrc,
        (__attribute__((address_space(3))) unsigned int*)ldst, 16, 0, 0);
}

// ---- fused prep: blocks [0,512) pack K/V, blocks [512,4608) sum biases ----
__global__ __launch_bounds__(256) void prep_fused(
    const float* __restrict__ K, const float* __restrict__ V,
    const int* __restrict__ imask,
    const float* __restrict__ b0, const float* __restrict__ b1,
    const float* __restrict__ b2, const float* __restrict__ b3,
    __bf16* __restrict__ Kp, __bf16* __restrict__ Vp, float* __restrict__ bs)
{
    __shared__ __align__(16) __bf16 Ks[64][136];
    __shared__ __align__(16) __bf16 Vs[64][136];
    const int bid = blockIdx.x;
    const int tid = threadIdx.x;

    if (bid >= 512) {
        // bias_sum: float4 per thread
        const int i = (bid - 512) * 256 + tid;
        const float4 a = ((const float4*)b0)[i];
        const float4 c = ((const float4*)b1)[i];
        const float4 d = ((const float4*)b2)[i];
        const float4 e = ((const float4*)b3)[i];
        float4 r;
        r.x = a.x + c.x + d.x + e.x;
        r.y = a.y + c.y + d.y + e.y;
        r.z = a.z + c.z + d.z + e.z;
        r.w = a.w + c.w + d.w + e.w;
        ((float4*)bs)[i] = r;
        return;
    }

    // pack_kv: c = chunk, b = batch
    const int c = bid & 31;
    const int b = bid >> 5;
    const int m0 = c * 64;
    const float* Kb = K + (size_t)b * Nc * Dc;
    const float* Vb = V + (size_t)b * Nc * Dc;
    const int* imb = imask + b * Nc;

    #pragma unroll
    for (int it = 0; it < 8; ++it) {
        const int idx = it * 256 + tid;
        const int row = idx >> 5;
        const int c4  = idx & 31;
        const int gm  = m0 + row;
        const float msk = imb[gm] ? 1.0f : 0.0f;
        const float4 kf = ((const float4*)(Kb + (size_t)gm * Dc))[c4];
        const float4 vf = ((const float4*)(Vb + (size_t)gm * Dc))[c4];
        bf16x4 kb, vb;
        kb[0] = (__bf16)(kf.x * msk); kb[1] = (__bf16)(kf.y * msk);
        kb[2] = (__bf16)(kf.z * msk); kb[3] = (__bf16)(kf.w * msk);
        vb[0] = (__bf16)(vf.x * msk); vb[1] = (__bf16)(vf.y * msk);
        vb[2] = (__bf16)(vf.z * msk); vb[3] = (__bf16)(vf.w * msk);
        *(bf16x4*)&Ks[row][c4 * 4] = kb;
        *(bf16x4*)&Vs[row][c4 * 4] = vb;
    }
    __syncthreads();

    const size_t chunk_base = (size_t)(b * NCHUNK + c) * CHUNK_ELEMS;
    #pragma unroll
    for (int i = 0; i < 4; ++i) {
        const int s = i * 256 + tid;     // slice id: 16 frags x 64 lanes
        const int f = s >> 6;
        const int l = s & 63;
        const int quad = (l >> 4) & 3;
        const int l15  = l & 15;
        {   // K frag f=jt*4+kd: contiguous 8 d at row jt*16+l15
            const int jt = f >> 2, kd = f & 3;
            const bf16x8 kv = *(const bf16x8*)&Ks[jt * 16 + l15][kd * 32 + quad * 8];
            *(bf16x8*)&Kp[chunk_base + (size_t)f * 512 + l * 8] = kv;
        }
        {   // V frag f=kj*8+dt: gather 8 keys at column dt*16+l15
            const int kj = f >> 3, dt = f & 7;
            bf16x8 vv;
            #pragma unroll
            for (int j = 0; j < 8; ++j)
                vv[j] = Vs[kj * 32 + quad * 8 + j][dt * 16 + l15];
            *(bf16x8*)&Vp[chunk_base + (size_t)f * 512 + l * 8] = vv;
        }
    }
}

// ---- main: paired-tile MFMA flash attention, double-buffered DMA ----
// grid (b=16, pair=16); block = 4 waves = 64 q-rows per tile; each block
// processes tiles p and 31-p sequentially -> uniform 33 chunk-iterations.
// blockIdx.x = b: round-robin XCD dispatch gives each XCD only 2 b-values,
// so its 2.1MB slice of K/V packs is L2-resident.
__global__ __launch_bounds__(256) void attn_paired(
    const float* __restrict__ Q,
    const __bf16* __restrict__ Kp, const __bf16* __restrict__ Vp,
    const float* __restrict__ bias, const int* __restrict__ emask,
    float* __restrict__ out)
{
    __shared__ __align__(16) __bf16 Kl[2][16 * 512];   // 2 x 16KB
    __shared__ __align__(16) __bf16 Vl[2][16 * 512];   // 2 x 16KB
    __shared__ __align__(16) __bf16 Pl[4][16][72];

    const int tid  = threadIdx.x;
    const int w    = tid >> 6;
    const int lane = tid & 63;
    const int quad = lane >> 4;
    const int l15  = lane & 15;
    const int b = blockIdx.x;
    const int p = blockIdx.y;

    const float*  Qb  = Q + (size_t)b * Nc * Dc;
    const int*    emb = emask + b * Nc;
    const __bf16* Kpb = Kp + (size_t)b * NCHUNK * CHUNK_ELEMS;
    const __bf16* Vpb = Vp + (size_t)b * NCHUNK * CHUNK_ELEMS;

    for (int t = 0; t < 2; ++t) {
        const int ti  = t ? (31 - p) : p;
        const int q0w = ti * 64 + w * 16;
        const int nch = ti + 1;

        // ---- Q fragments (emask + SCALE folded) ----
        bf16x8 qfrag[4];
        {
            const int row = q0w + l15;
            const float qs = emb[row] ? SCALE_F : 0.0f;
            const float4* qr = (const float4*)(Qb + (size_t)row * Dc);
            #pragma unroll
            for (int kd = 0; kd < 4; ++kd) {
                const float4 xx = qr[kd * 8 + quad * 2];
                const float4 yy = qr[kd * 8 + quad * 2 + 1];
                qfrag[kd][0] = (__bf16)(xx.x * qs); qfrag[kd][1] = (__bf16)(xx.y * qs);
                qfrag[kd][2] = (__bf16)(xx.z * qs); qfrag[kd][3] = (__bf16)(xx.w * qs);
                qfrag[kd][4] = (__bf16)(yy.x * qs); qfrag[kd][5] = (__bf16)(yy.y * qs);
                qfrag[kd][6] = (__bf16)(yy.z * qs); qfrag[kd][7] = (__bf16)(yy.w * qs);
            }
        }

        f32x4 oacc[8];
        #pragma unroll
        for (int dt = 0; dt < 8; ++dt) { oacc[dt][0]=0.f; oacc[dt][1]=0.f; oacc[dt][2]=0.f; oacc[dt][3]=0.f; }
        float mrun[4] = {-INFINITY, -INFINITY, -INFINITY, -INFINITY};
        float lrun[4] = {0.f, 0.f, 0.f, 0.f};

        // ---- prologue: DMA chunk 0 into buf 0; bias regs for chunk 0 ----
        #pragma unroll
        for (int i = 0; i < 4; ++i) {
            const int seg = w * 4 + i;
            gload_lds16(Kpb + seg * 512 + lane * 8, &Kl[0][seg * 512]);
            gload_lds16(Vpb + seg * 512 + lane * 8, &Vl[0][seg * 512]);
        }
        float bcur[4][4];
        #pragma unroll
        for (int jt = 0; jt < 4; ++jt)
            #pragma unroll
            for (int reg = 0; reg < 4; ++reg)
                bcur[jt][reg] = bias[(size_t)(q0w + quad * 4 + reg) * Nc + jt * 16 + l15];
        __syncthreads();   // drain: chunk-0 DMA landed

        for (int c = 0; c < nch; ++c) {
            const int cb = c & 1;
            const bool more = (c + 1) < nch;

            // ---- prefetch chunk c+1: DMA into other buffer + bias regs ----
            if (more) {
                const size_t off = (size_t)(c + 1) * CHUNK_ELEMS;
                #pragma unroll
                for (int i = 0; i < 4; ++i) {
                    const int seg = w * 4 + i;
                    gload_lds16(Kpb + off + seg * 512 + lane * 8, &Kl[cb ^ 1][seg * 512]);
                    gload_lds16(Vpb + off + seg * 512 + lane * 8, &Vl[cb ^ 1][seg * 512]);
                }
            }
            float bnext[4][4];
            if (more) {
                const int m1 = (c + 1) * 64;
                #pragma unroll
                for (int jt = 0; jt < 4; ++jt)
                    #pragma unroll
                    for (int reg = 0; reg < 4; ++reg)
                        bnext[jt][reg] = bias[(size_t)(q0w + quad * 4 + reg) * Nc + m1 + jt * 16 + l15];
            }

            // ---- S = (Q*SCALE) K^T ----
            f32x4 sc[4];
            #pragma unroll
            for (int jt = 0; jt < 4; ++jt) { sc[jt][0]=0.f; sc[jt][1]=0.f; sc[jt][2]=0.f; sc[jt][3]=0.f; }
            #pragma unroll
            for (int jt = 0; jt < 4; ++jt)
                #pragma unroll
                for (int kd = 0; kd < 4; ++kd) {
                    const bf16x8 bfr = *(const bf16x8*)&Kl[cb][(jt * 4 + kd) * 512 + lane * 8];
                    sc[jt] = __builtin_amdgcn_mfma_f32_16x16x32_bf16(qfrag[kd], bfr, sc[jt], 0, 0, 0);
                }

            // ---- bias add (+ causal only on diagonal chunk) ----
            if (c == ti) {
                const int m0 = c * 64;
                #pragma unroll
                for (int jt = 0; jt < 4; ++jt)
                    #pragma unroll
                    for (int reg = 0; reg < 4; ++reg) {
                        const int gr = q0w + quad * 4 + reg;
                        const int gc = m0 + jt * 16 + l15;
                        const float s = sc[jt][reg] + bcur[jt][reg];
                        sc[jt][reg] = (gc > gr) ? -INFINITY : s;
                    }
            } else {
                #pragma unroll
                for (int jt = 0; jt < 4; ++jt)
                    #pragma unroll
                    for (int reg = 0; reg < 4; ++reg)
                        sc[jt][reg] += bcur[jt][reg];
            }

            // ---- online softmax (row = quad*4+reg, spread over 16 lanes) ----
            float mloc[4];
            #pragma unroll
            for (int reg = 0; reg < 4; ++reg)
                mloc[reg] = fmaxf(fmaxf(sc[0][reg], sc[1][reg]), fmaxf(sc[2][reg], sc[3][reg]));
            #pragma unroll
            for (int off = 1; off <= 8; off <<= 1)
                #pragma unroll
                for (int reg = 0; reg < 4; ++reg)
                    mloc[reg] = fmaxf(mloc[reg], __shfl_xor(mloc[reg], off, 64));
            float lloc[4];
            #pragma unroll
            for (int reg = 0; reg < 4; ++reg) {
                const float mn = fmaxf(mrun[reg], mloc[reg]);
                const float alpha = __expf(mrun[reg] - mn);
                mrun[reg] = mn;
                lrun[reg] *= alpha;
                #pragma unroll
                for (int dt = 0; dt < 8; ++dt) oacc[dt][reg] *= alpha;
                float ls = 0.f;
                #pragma unroll
                for (int jt = 0; jt < 4; ++jt) {
                    const float pv = __expf(sc[jt][reg] - mn);
                    sc[jt][reg] = pv;
                    ls += pv;
                }
                lloc[reg] = ls;
            }
            #pragma unroll
            for (int off = 1; off <= 8; off <<= 1)
                #pragma unroll
                for (int reg = 0; reg < 4; ++reg)
                    lloc[reg] += __shfl_xor(lloc[reg], off, 64);
            #pragma unroll
            for (int reg = 0; reg < 4; ++reg) lrun[reg] += lloc[reg];

            // ---- P: C-layout -> LDS -> A-layout ----
            #pragma unroll
            for (int jt = 0; jt < 4; ++jt)
                #pragma unroll
                for (int reg = 0; reg < 4; ++reg)
                    Pl[w][quad * 4 + reg][jt * 16 + l15] = (__bf16)sc[jt][reg];
            // same-wave write->read; compiler inserts lgkmcnt wait

            // ---- O += P V ----
            #pragma unroll
            for (int kj = 0; kj < 2; ++kj) {
                const bf16x8 pa = *(const bf16x8*)&Pl[w][l15][kj * 32 + quad * 8];
                #pragma unroll
                for (int dt = 0; dt < 8; ++dt) {
                    const bf16x8 vb = *(const bf16x8*)&Vl[cb][(kj * 8 + dt) * 512 + lane * 8];
                    oacc[dt] = __builtin_amdgcn_mfma_f32_16x16x32_bf16(pa, vb, oacc[dt], 0, 0, 0);
                }
            }

            // single barrier per chunk: (1) all waves done reading buf[cb]
            // before next iter's DMA overwrites it; (2) vmcnt drain => DMA(c+1)
            // + bias(c+1) landed (issued ~1500 cyc ago -> near-free).
            __syncthreads();

            if (more) {
                #pragma unroll
                for (int jt = 0; jt < 4; ++jt)
                    #pragma unroll
                    for (int reg = 0; reg < 4; ++reg)
                        bcur[jt][reg] = bnext[jt][reg];
            }
        }

        // ---- epilogue: O / l ----
        #pragma unroll
        for (int reg = 0; reg < 4; ++reg) {
            const float inv = 1.0f / lrun[reg];
            const int gr = q0w + quad * 4 + reg;
            float* orow = out + ((size_t)b * Nc + gr) * Dc;
            #pragma unroll
            for (int dt = 0; dt < 8; ++dt)
                orow[dt * 16 + l15] = oacc[dt][reg] * inv;
        }
        // loop's final __syncthreads() already separates this tile's LDS
        // readers from next tile's prologue DMA.
    }
}

// ---- legacy fallback (in-kernel staging, 4 bias reads) for tiny ws ----
__global__ __launch_bounds__(256) void attn_mfma_legacy(
    const float* __restrict__ Q, const float* __restrict__ K, const float* __restrict__ V,
    const float* __restrict__ p0, const float* __restrict__ p1,
    const float* __restrict__ p2, const float* __restrict__ p3,
    const int* __restrict__ imask, const int* __restrict__ emask,
    float* __restrict__ out)
{
    __shared__ __align__(16) __bf16 Klds[64][136];
    __shared__ __align__(16) __bf16 Vt[128][72];
    __shared__ __align__(16) __bf16 Plds[4][16][72];
    const int tid  = threadIdx.x;
    const int w    = tid >> 6;
    const int lane = tid & 63;
    const int quad = lane >> 4;
    const int l15  = lane & 15;
    const int b = blockIdx.y;
    const int x = blockIdx.x, yy = blockIdx.y;
    const int ti = (yy < 8) ? x : (31 - x);
    const int q0 = ti * 64, q0w = q0 + w * 16;
    const float* Qb = Q + (size_t)b * Nc * Dc;
    const float* Kb = K + (size_t)b * Nc * Dc;
    const float* Vb = V + (size_t)b * Nc * Dc;
    const int* imb = imask + b * Nc;

    bf16x8 qfrag[4];
    {
        const int row = q0w + l15;
        const float qs = emask[b * Nc + row] ? SCALE_F : 0.0f;
        const float4* qr = (const float4*)(Qb + (size_t)row * Dc);
        #pragma unroll
        for (int kd = 0; kd < 4; ++kd) {
            const float4 xv = qr[kd * 8 + quad * 2];
            const float4 yv = qr[kd * 8 + quad * 2 + 1];
            qfrag[kd][0]=(__bf16)(xv.x*qs); qfrag[kd][1]=(__bf16)(xv.y*qs);
            qfrag[kd][2]=(__bf16)(xv.z*qs); qfrag[kd][3]=(__bf16)(xv.w*qs);
            qfrag[kd][4]=(__bf16)(yv.x*qs); qfrag[kd][5]=(__bf16)(yv.y*qs);
            qfrag[kd][6]=(__bf16)(yv.z*qs); qfrag[kd][7]=(__bf16)(yv.w*qs);
        }
    }
    f32x4 oacc[8];
    #pragma unroll
    for (int dt = 0; dt < 8; ++dt){oacc[dt][0]=0.f;oacc[dt][1]=0.f;oacc[dt][2]=0.f;oacc[dt][3]=0.f;}
    float mrun[4]={-INFINITY,-INFINITY,-INFINITY,-INFINITY}, lrun[4]={0.f,0.f,0.f,0.f};

    for (int m0 = 0; m0 <= q0; m0 += 64) {
        __syncthreads();
        #pragma unroll
        for (int it = 0; it < 8; ++it) {
            const int idx = it * 256 + tid;
            const int row = idx >> 5, c4 = idx & 31;
            const int gm = m0 + row;
            const float msk = imb[gm] ? 1.0f : 0.0f;
            const float4 kf = ((const float4*)(Kb + (size_t)gm * Dc))[c4];
            const float4 vf = ((const float4*)(Vb + (size_t)gm * Dc))[c4];
            bf16x4 kb;
            kb[0]=(__bf16)(kf.x*msk); kb[1]=(__bf16)(kf.y*msk);
            kb[2]=(__bf16)(kf.z*msk); kb[3]=(__bf16)(kf.w*msk);
            *(bf16x4*)&Klds[row][c4*4] = kb;
            Vt[c4*4+0][row]=(__bf16)(vf.x*msk); Vt[c4*4+1][row]=(__bf16)(vf.y*msk);
            Vt[c4*4+2][row]=(__bf16)(vf.z*msk); Vt[c4*4+3][row]=(__bf16)(vf.w*msk);
        }
        __syncthreads();
        f32x4 sc[4];
        #pragma unroll
        for (int jt = 0; jt < 4; ++jt){sc[jt][0]=0.f;sc[jt][1]=0.f;sc[jt][2]=0.f;sc[jt][3]=0.f;}
        #pragma unroll
        for (int jt = 0; jt < 4; ++jt)
            #pragma unroll
            for (int kd = 0; kd < 4; ++kd) {
                const bf16x8 bfr = *(const bf16x8*)&Klds[jt*16+l15][kd*32+quad*8];
                sc[jt] = __builtin_amdgcn_mfma_f32_16x16x32_bf16(qfrag[kd], bfr, sc[jt], 0, 0, 0);
            }
        #pragma unroll
        for (int jt = 0; jt < 4; ++jt)
            #pragma unroll
            for (int reg = 0; reg < 4; ++reg) {
                const int gr = q0w + quad*4 + reg;
                const int gc = m0 + jt*16 + l15;
                const size_t boff = (size_t)gr * Nc + gc;
                const float bsx = p0[boff] + p1[boff] + p2[boff] + p3[boff];
                const float s = sc[jt][reg] + bsx;
                sc[jt][reg] = (gc > gr) ? -INFINITY : s;
            }
        float mloc[4];
        #pragma unroll
        for (int reg = 0; reg < 4; ++reg)
            mloc[reg] = fmaxf(fmaxf(sc[0][reg], sc[1][reg]), fmaxf(sc[2][reg], sc[3][reg]));
        #pragma unroll
        for (int off = 1; off <= 8; off <<= 1)
            #pragma unroll
            for (int reg = 0; reg < 4; ++reg)
                mloc[reg] = fmaxf(mloc[reg], __shfl_xor(mloc[reg], off, 64));
        float lloc[4];
        #pragma unroll
        for (int reg = 0; reg < 4; ++reg) {
            const float mn = fmaxf(mrun[reg], mloc[reg]);
            const float alpha = __expf(mrun[reg] - mn);
            mrun[reg] = mn; lrun[reg] *= alpha;
            #pragma unroll
            for (int dt = 0; dt < 8; ++dt) oacc[dt][reg] *= alpha;
            float ls = 0.f;
            #pragma unroll
            for (int jt = 0; jt < 4; ++jt) {
                const float pv = __expf(sc[jt][reg] - mn);
                sc[jt][reg] = pv; ls += pv;
            }
            lloc[reg] = ls;
        }
        #pragma unroll
        for (int off = 1; off <= 8; off <<= 1)
            #pragma unroll
            for (int reg = 0; reg < 4; ++reg)
                lloc[reg] += __shfl_xor(lloc[reg], off, 64);
        #pragma unroll
        for (int reg = 0; reg < 4; ++reg) lrun[reg] += lloc[reg];
        #pragma unroll
        for (int jt = 0; jt < 4; ++jt)
            #pragma unroll
            for (int reg = 0; reg < 4; ++reg)
                Plds[w][quad*4+reg][jt*16+l15] = (__bf16)sc[jt][reg];
        #pragma unroll
        for (int kj = 0; kj < 2; ++kj) {
            const bf16x8 pa = *(const bf16x8*)&Plds[w][l15][kj*32+quad*8];
            #pragma unroll
            for (int dt = 0; dt < 8; ++dt) {
                const bf16x8 vb = *(const bf16x8*)&Vt[dt*16+l15][kj*32+quad*8];
                oacc[dt] = __builtin_amdgcn_mfma_f32_16x16x32_bf16(pa, vb, oacc[dt], 0, 0, 0);
            }
        }
    }
    #pragma unroll
    for (int reg = 0; reg < 4; ++reg) {
        const float inv = 1.0f / lrun[reg];
        const int gr = q0w + quad*4 + reg;
        float* orow = out + ((size_t)b * Nc + gr) * Dc;
        #pragma unroll
        for (int dt = 0; dt < 8; ++dt)
            orow[dt*16+l15] = oacc[dt][reg] * inv;
    }
}

extern "C" void kernel_launch(void* const* d_in, const int* in_sizes, int n_in,
                              void* d_out, int out_size, void* d_ws, size_t ws_size,
                              hipStream_t stream) {
    const float* Q  = (const float*)d_in[0];
    const float* K  = (const float*)d_in[1];
    const float* V  = (const float*)d_in[2];
    const float* b0 = (const float*)d_in[3];
    const float* b1 = (const float*)d_in[4];
    const float* b2 = (const float*)d_in[5];
    const float* b3 = (const float*)d_in[6];
    const int* im   = (const int*)d_in[7];
    const int* em   = (const int*)d_in[8];
    float* out      = (float*)d_out;

    if (ws_size >= KPACK_BYTES + VPACK_BYTES + BIAS_BYTES) {
        __bf16* Kp = (__bf16*)d_ws;
        __bf16* Vp = (__bf16*)((char*)d_ws + KPACK_BYTES);
        float*  bs = (float*)((char*)d_ws + KPACK_BYTES + VPACK_BYTES);
        prep_fused<<<512 + (Nc * Nc / 4) / 256, 256, 0, stream>>>(
            K, V, im, b0, b1, b2, b3, Kp, Vp, bs);
        attn_paired<<<dim3(Bc, 16), 256, 0, stream>>>(Q, Kp, Vp, bs, em, out);
    } else {
        attn_mfma_legacy<<<dim3(NCHUNK, Bc), 256, 0, stream>>>(
            Q, K, V, b0, b1, b2, b3, im, em, out);
    }
}

// Round 5
// 233.470 us; speedup vs baseline: 14.1498x; 1.0154x over previous
//
#include <hip/hip_runtime.h>
#include <math.h>

// (B, N, D) = (16, 2048, 128)
constexpr int Bc = 16;
constexpr int Nc = 2048;
constexpr int Dc = 128;
constexpr int NCHUNK = Nc / 64;          // 32 key-chunks of 64
constexpr float SCALE_F = 0.08838834764831845f;  // 1/sqrt(128)

typedef __bf16 bf16x8 __attribute__((ext_vector_type(8)));
typedef __bf16 bf16x4 __attribute__((ext_vector_type(4)));
typedef float  f32x4  __attribute__((ext_vector_type(4)));

// ws layout: Kpack 8MB | Vpack 8MB | bias_sum 16MB
constexpr size_t KPACK_BYTES = (size_t)Bc * NCHUNK * 16 * 64 * 16;
constexpr size_t VPACK_BYTES = KPACK_BYTES;
constexpr size_t BIAS_BYTES  = (size_t)Nc * Nc * 4;
constexpr int CHUNK_ELEMS = 16 * 64 * 8;  // 8192 bf16 = 16KB per chunk

__device__ __forceinline__ void gload_lds16(const __bf16* gsrc, __bf16* ldst) {
    // 16B per lane; LDS dest = wave-uniform base + lane*16 (HW rule).
    __builtin_amdgcn_global_load_lds(
        (const __attribute__((address_space(1))) unsigned int*)gsrc,
        (__attribute__((address_space(3))) unsigned int*)ldst, 16, 0, 0);
}

// ---- DPP 16-lane row reductions (VALU pipe, no LDS/lgkm) ----
template<int CTRL>
__device__ __forceinline__ float dpp_mv(float v) {
    return __builtin_bit_cast(float,
        __builtin_amdgcn_update_dpp(0, __builtin_bit_cast(int, v),
                                    CTRL, 0xF, 0xF, true));
}
// butterfly over the 16-lane DPP row: xor1(quad_perm 1032), xor2(quad_perm 2301),
// half_mirror (combines quads within octet), mirror (combines octets).
__device__ __forceinline__ float rmax16(float v) {
    v = fmaxf(v, dpp_mv<0xB1>(v));
    v = fmaxf(v, dpp_mv<0x4E>(v));
    v = fmaxf(v, dpp_mv<0x141>(v));
    v = fmaxf(v, dpp_mv<0x140>(v));
    return v;
}
__device__ __forceinline__ float rsum16(float v) {
    v += dpp_mv<0xB1>(v);
    v += dpp_mv<0x4E>(v);
    v += dpp_mv<0x141>(v);
    v += dpp_mv<0x140>(v);
    return v;
}

// ---- fused prep: blocks [0,512) pack K/V, blocks [512,4608) sum biases ----
__global__ __launch_bounds__(256) void prep_fused(
    const float* __restrict__ K, const float* __restrict__ V,
    const int* __restrict__ imask,
    const float* __restrict__ b0, const float* __restrict__ b1,
    const float* __restrict__ b2, const float* __restrict__ b3,
    __bf16* __restrict__ Kp, __bf16* __restrict__ Vp, float* __restrict__ bs)
{
    __shared__ __align__(16) __bf16 Ks[64][136];
    __shared__ __align__(16) __bf16 Vs[64][136];
    const int bid = blockIdx.x;
    const int tid = threadIdx.x;

    if (bid >= 512) {
        const int i = (bid - 512) * 256 + tid;
        const float4 a = ((const float4*)b0)[i];
        const float4 c = ((const float4*)b1)[i];
        const float4 d = ((const float4*)b2)[i];
        const float4 e = ((const float4*)b3)[i];
        float4 r;
        r.x = a.x + c.x + d.x + e.x;
        r.y = a.y + c.y + d.y + e.y;
        r.z = a.z + c.z + d.z + e.z;
        r.w = a.w + c.w + d.w + e.w;
        ((float4*)bs)[i] = r;
        return;
    }

    const int c = bid & 31;
    const int b = bid >> 5;
    const int m0 = c * 64;
    const float* Kb = K + (size_t)b * Nc * Dc;
    const float* Vb = V + (size_t)b * Nc * Dc;
    const int* imb = imask + b * Nc;

    #pragma unroll
    for (int it = 0; it < 8; ++it) {
        const int idx = it * 256 + tid;
        const int row = idx >> 5;
        const int c4  = idx & 31;
        const int gm  = m0 + row;
        const float msk = imb[gm] ? 1.0f : 0.0f;
        const float4 kf = ((const float4*)(Kb + (size_t)gm * Dc))[c4];
        const float4 vf = ((const float4*)(Vb + (size_t)gm * Dc))[c4];
        bf16x4 kb, vb;
        kb[0] = (__bf16)(kf.x * msk); kb[1] = (__bf16)(kf.y * msk);
        kb[2] = (__bf16)(kf.z * msk); kb[3] = (__bf16)(kf.w * msk);
        vb[0] = (__bf16)(vf.x * msk); vb[1] = (__bf16)(vf.y * msk);
        vb[2] = (__bf16)(vf.z * msk); vb[3] = (__bf16)(vf.w * msk);
        *(bf16x4*)&Ks[row][c4 * 4] = kb;
        *(bf16x4*)&Vs[row][c4 * 4] = vb;
    }
    __syncthreads();

    const size_t chunk_base = (size_t)(b * NCHUNK + c) * CHUNK_ELEMS;
    #pragma unroll
    for (int i = 0; i < 4; ++i) {
        const int s = i * 256 + tid;
        const int f = s >> 6;
        const int l = s & 63;
        const int quad = (l >> 4) & 3;
        const int l15  = l & 15;
        {   // K frag f=jt*4+kd
            const int jt = f >> 2, kd = f & 3;
            const bf16x8 kv = *(const bf16x8*)&Ks[jt * 16 + l15][kd * 32 + quad * 8];
            *(bf16x8*)&Kp[chunk_base + (size_t)f * 512 + l * 8] = kv;
        }
        {   // V frag f=kj*8+dt
            const int kj = f >> 3, dt = f & 7;
            bf16x8 vv;
            #pragma unroll
            for (int j = 0; j < 8; ++j)
                vv[j] = Vs[kj * 32 + quad * 8 + j][dt * 16 + l15];
            *(bf16x8*)&Vp[chunk_base + (size_t)f * 512 + l * 8] = vv;
        }
    }
}

// ---- main: pipelined MFMA flash attention ----
// grid (b=16, s=32): ti = s<16 ? s : 47-s.
//  - co-resident pair (b,s)/(b,s+16) (ids differ by 256) does (s+1)+(32-s)=33
//    chunks -> balanced makespan at 2 blocks/CU (2 waves/SIMD).
//  - id%8 = b%8 -> each XCD reads only 2 b-slices of the packs (~4MB, L2-fit).
// Pipeline per iter: softmax(c) -> PV(c) -> barrier -> DMA(c+2) -> QK(c+1),
// so each DMA has a full iteration of lead time before its vmcnt drain.
__global__ __launch_bounds__(256) void attn_pipe(
    const float* __restrict__ Q,
    const __bf16* __restrict__ Kp, const __bf16* __restrict__ Vp,
    const float* __restrict__ bias, const int* __restrict__ emask,
    float* __restrict__ out)
{
    __shared__ __align__(16) __bf16 Kl[2][16 * 512];   // 2 x 16KB
    __shared__ __align__(16) __bf16 Vl[2][16 * 512];   // 2 x 16KB
    __shared__ __align__(16) __bf16 Pl[4][16][72];

    const int tid  = threadIdx.x;
    const int w    = tid >> 6;
    const int lane = tid & 63;
    const int quad = lane >> 4;
    const int l15  = lane & 15;
    const int b = blockIdx.x;
    const int s = blockIdx.y;
    const int ti  = (s < 16) ? s : (47 - s);
    const int q0w = ti * 64 + w * 16;
    const int nch = ti + 1;

    const float*  Qb  = Q + (size_t)b * Nc * Dc;
    const __bf16* Kpb = Kp + (size_t)b * NCHUNK * CHUNK_ELEMS;
    const __bf16* Vpb = Vp + (size_t)b * NCHUNK * CHUNK_ELEMS;

    // per-lane bias row pointers (row = q0w + quad*4 + reg, col base = l15)
    const float* bp[4];
    #pragma unroll
    for (int reg = 0; reg < 4; ++reg)
        bp[reg] = bias + (size_t)(q0w + quad * 4 + reg) * Nc + l15;

    // ---- Q fragments (emask + SCALE folded) ----
    bf16x8 qfrag[4];
    {
        const int row = q0w + l15;
        const float qs = emask[b * Nc + row] ? SCALE_F : 0.0f;
        const float4* qr = (const float4*)(Qb + (size_t)row * Dc);
        #pragma unroll
        for (int kd = 0; kd < 4; ++kd) {
            const float4 xx = qr[kd * 8 + quad * 2];
            const float4 yy = qr[kd * 8 + quad * 2 + 1];
            qfrag[kd][0] = (__bf16)(xx.x * qs); qfrag[kd][1] = (__bf16)(xx.y * qs);
            qfrag[kd][2] = (__bf16)(xx.z * qs); qfrag[kd][3] = (__bf16)(xx.w * qs);
            qfrag[kd][4] = (__bf16)(yy.x * qs); qfrag[kd][5] = (__bf16)(yy.y * qs);
            qfrag[kd][6] = (__bf16)(yy.z * qs); qfrag[kd][7] = (__bf16)(yy.w * qs);
        }
    }

    f32x4 oacc[8];
    #pragma unroll
    for (int dt = 0; dt < 8; ++dt) { oacc[dt][0]=0.f; oacc[dt][1]=0.f; oacc[dt][2]=0.f; oacc[dt][3]=0.f; }
    float mrun[4] = {-INFINITY, -INFINITY, -INFINITY, -INFINITY};
    float lrun[4] = {0.f, 0.f, 0.f, 0.f};

    // ---- prologue: DMA chunk 0 -> buf0; bias(0) ----
    #pragma unroll
    for (int i = 0; i < 4; ++i) {
        const int seg = w * 4 + i;
        gload_lds16(Kpb + seg * 512 + lane * 8, &Kl[0][seg * 512]);
        gload_lds16(Vpb + seg * 512 + lane * 8, &Vl[0][seg * 512]);
    }
    float bcur[4][4], bnext[4][4];
    #pragma unroll
    for (int jt = 0; jt < 4; ++jt)
        #pragma unroll
        for (int reg = 0; reg < 4; ++reg)
            bcur[jt][reg] = bp[reg][jt * 16];
    __syncthreads();   // drain: chunk-0 DMA landed

    // ---- QK(0) ----
    f32x4 sc[4];
    #pragma unroll
    for (int jt = 0; jt < 4; ++jt) { sc[jt][0]=0.f; sc[jt][1]=0.f; sc[jt][2]=0.f; sc[jt][3]=0.f; }
    #pragma unroll
    for (int jt = 0; jt < 4; ++jt)
        #pragma unroll
        for (int kd = 0; kd < 4; ++kd) {
            const bf16x8 bfr = *(const bf16x8*)&Kl[0][(jt * 4 + kd) * 512 + lane * 8];
            sc[jt] = __builtin_amdgcn_mfma_f32_16x16x32_bf16(qfrag[kd], bfr, sc[jt], 0, 0, 0);
        }
    if (nch > 1) {
        #pragma unroll
        for (int i = 0; i < 4; ++i) {
            const int seg = w * 4 + i;
            gload_lds16(Kpb + CHUNK_ELEMS + seg * 512 + lane * 8, &Kl[1][seg * 512]);
            gload_lds16(Vpb + CHUNK_ELEMS + seg * 512 + lane * 8, &Vl[1][seg * 512]);
        }
        #pragma unroll
        for (int jt = 0; jt < 4; ++jt)
            #pragma unroll
            for (int reg = 0; reg < 4; ++reg)
                bnext[jt][reg] = bp[reg][64 + jt * 16];
    }

    for (int c = 0; c < nch; ++c) {
        const int cb = c & 1;

        // ---- bias add (+ causal only on diagonal chunk) ----
        if (c == ti) {
            const int m0 = c * 64;
            #pragma unroll
            for (int jt = 0; jt < 4; ++jt)
                #pragma unroll
                for (int reg = 0; reg < 4; ++reg) {
                    const int gr = q0w + quad * 4 + reg;
                    const int gc = m0 + jt * 16 + l15;
                    const float v = sc[jt][reg] + bcur[jt][reg];
                    sc[jt][reg] = (gc > gr) ? -INFINITY : v;
                }
        } else {
            #pragma unroll
            for (int jt = 0; jt < 4; ++jt)
                #pragma unroll
                for (int reg = 0; reg < 4; ++reg)
                    sc[jt][reg] += bcur[jt][reg];
        }

        // ---- online softmax (DPP 16-lane reductions; row = quad*4+reg) ----
        #pragma unroll
        for (int reg = 0; reg < 4; ++reg) {
            float mx = fmaxf(fmaxf(sc[0][reg], sc[1][reg]), fmaxf(sc[2][reg], sc[3][reg]));
            mx = rmax16(mx);
            const float mn = fmaxf(mrun[reg], mx);       // finite: diag col active
            const float alpha = __expf(mrun[reg] - mn);  // first chunk: exp(-inf)=0
            mrun[reg] = mn;
            lrun[reg] *= alpha;
            #pragma unroll
            for (int dt = 0; dt < 8; ++dt) oacc[dt][reg] *= alpha;
            float ls = 0.f;
            #pragma unroll
            for (int jt = 0; jt < 4; ++jt) {
                const float pv = __expf(sc[jt][reg] - mn);  // masked: exp(-inf)=0
                sc[jt][reg] = pv;
                ls += pv;
            }
            lrun[reg] += rsum16(ls);
        }

        // ---- P: C-layout -> LDS -> A-layout ----
        #pragma unroll
        for (int jt = 0; jt < 4; ++jt)
            #pragma unroll
            for (int reg = 0; reg < 4; ++reg)
                Pl[w][quad * 4 + reg][jt * 16 + l15] = (__bf16)sc[jt][reg];
        // same-wave write->read; compiler inserts lgkmcnt wait

        // ---- O += P V ----
        #pragma unroll
        for (int kj = 0; kj < 2; ++kj) {
            const bf16x8 pa = *(const bf16x8*)&Pl[w][l15][kj * 32 + quad * 8];
            #pragma unroll
            for (int dt = 0; dt < 8; ++dt) {
                const bf16x8 vb = *(const bf16x8*)&Vl[cb][(kj * 8 + dt) * 512 + lane * 8];
                oacc[dt] = __builtin_amdgcn_mfma_f32_16x16x32_bf16(pa, vb, oacc[dt], 0, 0, 0);
            }
        }

        // single barrier: all waves done reading Kl[cb]/Vl[cb]; vmcnt drain
        // covers DMA(c+1) (issued a full iteration ago -> near-free).
        __syncthreads();

        const bool n1 = (c + 1) < nch;
        const bool n2 = (c + 2) < nch;

        // ---- DMA chunk c+2 into buf[cb] (K(c)/V(c) both retired) ----
        if (n2) {
            const size_t off = (size_t)(c + 2) * CHUNK_ELEMS;
            #pragma unroll
            for (int i = 0; i < 4; ++i) {
                const int seg = w * 4 + i;
                gload_lds16(Kpb + off + seg * 512 + lane * 8, &Kl[cb][seg * 512]);
                gload_lds16(Vpb + off + seg * 512 + lane * 8, &Vl[cb][seg * 512]);
            }
        }

        // ---- QK(c+1) from Kl[cb^1] (landed: DMA'd last iter + barrier) ----
        if (n1) {
            #pragma unroll
            for (int jt = 0; jt < 4; ++jt) { sc[jt][0]=0.f; sc[jt][1]=0.f; sc[jt][2]=0.f; sc[jt][3]=0.f; }
            #pragma unroll
            for (int jt = 0; jt < 4; ++jt)
                #pragma unroll
                for (int kd = 0; kd < 4; ++kd) {
                    const bf16x8 bfr = *(const bf16x8*)&Kl[cb ^ 1][(jt * 4 + kd) * 512 + lane * 8];
                    sc[jt] = __builtin_amdgcn_mfma_f32_16x16x32_bf16(qfrag[kd], bfr, sc[jt], 0, 0, 0);
                }
            #pragma unroll
            for (int jt = 0; jt < 4; ++jt)
                #pragma unroll
                for (int reg = 0; reg < 4; ++reg)
                    bcur[jt][reg] = bnext[jt][reg];
        }
        if (n2) {
            const int m2 = (c + 2) * 64;
            #pragma unroll
            for (int jt = 0; jt < 4; ++jt)
                #pragma unroll
                for (int reg = 0; reg < 4; ++reg)
                    bnext[jt][reg] = bp[reg][m2 + jt * 16];
        }
    }

    // ---- epilogue: O / l ----
    #pragma unroll
    for (int reg = 0; reg < 4; ++reg) {
        const float inv = 1.0f / lrun[reg];
        const int gr = q0w + quad * 4 + reg;
        float* orow = out + ((size_t)b * Nc + gr) * Dc;
        #pragma unroll
        for (int dt = 0; dt < 8; ++dt)
            orow[dt * 16 + l15] = oacc[dt][reg] * inv;
    }
}

// ---- legacy fallback (in-kernel staging, 4 bias reads) for tiny ws ----
__global__ __launch_bounds__(256) void attn_mfma_legacy(
    const float* __restrict__ Q, const float* __restrict__ K, const float* __restrict__ V,
    const float* __restrict__ p0, const float* __restrict__ p1,
    const float* __restrict__ p2, const float* __restrict__ p3,
    const int* __restrict__ imask, const int* __restrict__ emask,
    float* __restrict__ out)
{
    __shared__ __align__(16) __bf16 Klds[64][136];
    __shared__ __align__(16) __bf16 Vt[128][72];
    __shared__ __align__(16) __bf16 Plds[4][16][72];
    const int tid  = threadIdx.x;
    const int w    = tid >> 6;
    const int lane = tid & 63;
    const int quad = lane >> 4;
    const int l15  = lane & 15;
    const int b = blockIdx.y;
    const int x = blockIdx.x, yy = blockIdx.y;
    const int ti = (yy < 8) ? x : (31 - x);
    const int q0 = ti * 64, q0w = q0 + w * 16;
    const float* Qb = Q + (size_t)b * Nc * Dc;
    const float* Kb = K + (size_t)b * Nc * Dc;
    const float* Vb = V + (size_t)b * Nc * Dc;
    const int* imb = imask + b * Nc;

    bf16x8 qfrag[4];
    {
        const int row = q0w + l15;
        const float qs = emask[b * Nc + row] ? SCALE_F : 0.0f;
        const float4* qr = (const float4*)(Qb + (size_t)row * Dc);
        #pragma unroll
        for (int kd = 0; kd < 4; ++kd) {
            const float4 xv = qr[kd * 8 + quad * 2];
            const float4 yv = qr[kd * 8 + quad * 2 + 1];
            qfrag[kd][0]=(__bf16)(xv.x*qs); qfrag[kd][1]=(__bf16)(xv.y*qs);
            qfrag[kd][2]=(__bf16)(xv.z*qs); qfrag[kd][3]=(__bf16)(xv.w*qs);
            qfrag[kd][4]=(__bf16)(yv.x*qs); qfrag[kd][5]=(__bf16)(yv.y*qs);
            qfrag[kd][6]=(__bf16)(yv.z*qs); qfrag[kd][7]=(__bf16)(yv.w*qs);
        }
    }
    f32x4 oacc[8];
    #pragma unroll
    for (int dt = 0; dt < 8; ++dt){oacc[dt][0]=0.f;oacc[dt][1]=0.f;oacc[dt][2]=0.f;oacc[dt][3]=0.f;}
    float mrun[4]={-INFINITY,-INFINITY,-INFINITY,-INFINITY}, lrun[4]={0.f,0.f,0.f,0.f};

    for (int m0 = 0; m0 <= q0; m0 += 64) {
        __syncthreads();
        #pragma unroll
        for (int it = 0; it < 8; ++it) {
            const int idx = it * 256 + tid;
            const int row = idx >> 5, c4 = idx & 31;
            const int gm = m0 + row;
            const float msk = imb[gm] ? 1.0f : 0.0f;
            const float4 kf = ((const float4*)(Kb + (size_t)gm * Dc))[c4];
            const float4 vf = ((const float4*)(Vb + (size_t)gm * Dc))[c4];
            bf16x4 kb;
            kb[0]=(__bf16)(kf.x*msk); kb[1]=(__bf16)(kf.y*msk);
            kb[2]=(__bf16)(kf.z*msk); kb[3]=(__bf16)(kf.w*msk);
            *(bf16x4*)&Klds[row][c4*4] = kb;
            Vt[c4*4+0][row]=(__bf16)(vf.x*msk); Vt[c4*4+1][row]=(__bf16)(vf.y*msk);
            Vt[c4*4+2][row]=(__bf16)(vf.z*msk); Vt[c4*4+3][row]=(__bf16)(vf.w*msk);
        }
        __syncthreads();
        f32x4 sc[4];
        #pragma unroll
        for (int jt = 0; jt < 4; ++jt){sc[jt][0]=0.f;sc[jt][1]=0.f;sc[jt][2]=0.f;sc[jt][3]=0.f;}
        #pragma unroll
        for (int jt = 0; jt < 4; ++jt)
            #pragma unroll
            for (int kd = 0; kd < 4; ++kd) {
                const bf16x8 bfr = *(const bf16x8*)&Klds[jt*16+l15][kd*32+quad*8];
                sc[jt] = __builtin_amdgcn_mfma_f32_16x16x32_bf16(qfrag[kd], bfr, sc[jt], 0, 0, 0);
            }
        #pragma unroll
        for (int jt = 0; jt < 4; ++jt)
            #pragma unroll
            for (int reg = 0; reg < 4; ++reg) {
                const int gr = q0w + quad*4 + reg;
                const int gc = m0 + jt*16 + l15;
                const size_t boff = (size_t)gr * Nc + gc;
                const float bsx = p0[boff] + p1[boff] + p2[boff] + p3[boff];
                const float v = sc[jt][reg] + bsx;
                sc[jt][reg] = (gc > gr) ? -INFINITY : v;
            }
        #pragma unroll
        for (int reg = 0; reg < 4; ++reg) {
            float mx = fmaxf(fmaxf(sc[0][reg], sc[1][reg]), fmaxf(sc[2][reg], sc[3][reg]));
            mx = rmax16(mx);
            const float mn = fmaxf(mrun[reg], mx);
            const float alpha = __expf(mrun[reg] - mn);
            mrun[reg] = mn; lrun[reg] *= alpha;
            #pragma unroll
            for (int dt = 0; dt < 8; ++dt) oacc[dt][reg] *= alpha;
            float ls = 0.f;
            #pragma unroll
            for (int jt = 0; jt < 4; ++jt) {
                const float pv = __expf(sc[jt][reg] - mn);
                sc[jt][reg] = pv; ls += pv;
            }
            lrun[reg] += rsum16(ls);
        }
        #pragma unroll
        for (int jt = 0; jt < 4; ++jt)
            #pragma unroll
            for (int reg = 0; reg < 4; ++reg)
                Plds[w][quad*4+reg][jt*16+l15] = (__bf16)sc[jt][reg];
        #pragma unroll
        for (int kj = 0; kj < 2; ++kj) {
            const bf16x8 pa = *(const bf16x8*)&Plds[w][l15][kj*32+quad*8];
            #pragma unroll
            for (int dt = 0; dt < 8; ++dt) {
                const bf16x8 vb = *(const bf16x8*)&Vt[dt*16+l15][kj*32+quad*8];
                oacc[dt] = __builtin_amdgcn_mfma_f32_16x16x32_bf16(pa, vb, oacc[dt], 0, 0, 0);
            }
        }
    }
    #pragma unroll
    for (int reg = 0; reg < 4; ++reg) {
        const float inv = 1.0f / lrun[reg];
        const int gr = q0w + quad*4 + reg;
        float* orow = out + ((size_t)b * Nc + gr) * Dc;
        #pragma unroll
        for (int dt = 0; dt < 8; ++dt)
            orow[dt*16+l15] = oacc[dt][reg] * inv;
    }
}

extern "C" void kernel_launch(void* const* d_in, const int* in_sizes, int n_in,
                              void* d_out, int out_size, void* d_ws, size_t ws_size,
                              hipStream_t stream) {
    const float* Q  = (const float*)d_in[0];
    const float* K  = (const float*)d_in[1];
    const float* V  = (const float*)d_in[2];
    const float* b0 = (const float*)d_in[3];
    const float* b1 = (const float*)d_in[4];
    const float* b2 = (const float*)d_in[5];
    const float* b3 = (const float*)d_in[6];
    const int* im   = (const int*)d_in[7];
    const int* em   = (const int*)d_in[8];
    float* out      = (float*)d_out;

    if (ws_size >= KPACK_BYTES + VPACK_BYTES + BIAS_BYTES) {
        __bf16* Kp = (__bf16*)d_ws;
        __bf16* Vp = (__bf16*)((char*)d_ws + KPACK_BYTES);
        float*  bs = (float*)((char*)d_ws + KPACK_BYTES + VPACK_BYTES);
        prep_fused<<<512 + (Nc * Nc / 4) / 256, 256, 0, stream>>>(
            K, V, im, b0, b1, b2, b3, Kp, Vp, bs);
        attn_pipe<<<dim3(Bc, 32), 256, 0, stream>>>(Q, Kp, Vp, bs, em, out);
    } else {
        attn_mfma_legacy<<<dim3(NCHUNK, Bc), 256, 0, stream>>>(
            Q, K, V, b0, b1, b2, b3, im, em, out);
    }
}